// Round 10
// baseline (609.112 us; speedup 1.0000x reference)
//
#include <hip/hip_runtime.h>
#include <stdint.h>

#define GAS __attribute__((address_space(1)))
#define LAS __attribute__((address_space(3)))

typedef __attribute__((ext_vector_type(8))) short short8;
typedef __attribute__((ext_vector_type(4))) float float4v;
typedef __attribute__((ext_vector_type(4))) unsigned int uint4v;

__device__ __forceinline__ unsigned short f2bf(float f) {
  union { float f; unsigned int u; } v; v.f = f;
  unsigned int r = v.u + 0x7fffu + ((v.u >> 16) & 1u);
  return (unsigned short)(r >> 16);
}

__device__ __forceinline__ void async_g2l16(const void* g, void* l) {
  __builtin_amdgcn_global_load_lds((const GAS unsigned int*)g,
                                   (LAS unsigned int*)l, 16, 0, 0);
}

__device__ __forceinline__ void vmem_drain() {
  asm volatile("s_waitcnt vmcnt(0)" ::: "memory");
}

// ---- Kernel A: normalize y -> bf16 fragment-major [t][og][cb][lane][8] ----
// (R5 layout, 16x16x32 B-operand map.) For t=dy*16+dx: fragment (og,cb) is
// 1KB; lane = q*16 + (o&15) holds o = og*16+(o&15), c = cb*32 + q*8 + j.
__global__ void knorm_y(const float* __restrict__ y, unsigned short* __restrict__ y_t2) {
  int o = blockIdx.x;
  int tid = threadIdx.x;
  const float* yo = y + o * 16384;
  float s = 0.f;
  for (int idx = tid; idx < 16384; idx += 256) { float v = yo[idx]; s += v * v; }
  for (int off = 32; off; off >>= 1) s += __shfl_down(s, off, 64);
  __shared__ float red[4];
  if ((tid & 63) == 0) red[tid >> 6] = s;
  __syncthreads();
  float rn = 1.0f / sqrtf(red[0] + red[1] + red[2] + red[3]);
  int og = o >> 4, ol = o & 15;
  for (int idx = tid; idx < 16384; idx += 256) {
    int c = idx >> 8, dy = (idx >> 4) & 15, dx = idx & 15;
    int t = dy * 16 + dx;
    int cb = c >> 5, q = (c >> 3) & 3, j = c & 7;
    size_t dst = (size_t)t * 4096 + (size_t)(og * 2 + cb) * 512 + (q * 16 + ol) * 8 + j;
    y_t2[dst] = f2bf(yo[idx] * rn);
  }
}

// ------- Kernel B: x (NCHW f32) -> x_t bf16 [n][h][w][c] swizzled, + s -----
// (R5 3-bit XOR swizzle: chunk = cc ^ (w&7) — measured 0 conflicts with the
// 16-row 16x16x32 A-read.)
__global__ void ktrans_x(const float* __restrict__ x, unsigned short* __restrict__ x_t,
                         float* __restrict__ s) {
  int h = blockIdx.x, n = blockIdx.y;
  int tid = threadIdx.x;
  __shared__ __align__(16) unsigned short tb[8192];
  __shared__ float sb[256];
  const float* xb = x + ((size_t)n * 64) * 16384 + h * 128;
  int w = tid & 127, half = tid >> 7;
  float acc = 0.f;
#pragma unroll
  for (int cs = 0; cs < 4; ++cs) {
    short8 tmp;
#pragma unroll
    for (int j = 0; j < 8; ++j) {
      int c = half * 32 + cs * 8 + j;
      float v = xb[(size_t)c * 16384 + w];
      tmp[j] = (short)f2bf(v);
      acc += v * v;
    }
    int chunk = (half * 4 + cs) ^ (w & 7);
    *(short8*)(tb + w * 64 + chunk * 8) = tmp;
  }
  sb[tid] = acc;
  __syncthreads();
  uint4v* dst = (uint4v*)(x_t + ((size_t)(n * 128 + h)) * 8192);
  const uint4v* src = (const uint4v*)tb;
  for (int idx = tid; idx < 1024; idx += 256) dst[idx] = src[idx];
  if (tid < 128) s[((size_t)(n * 128 + h)) * 128 + tid] = sb[tid] + sb[tid + 128];
}

// ---------------- Kernel D: separable 16x16 box sum of s -> 1/sqrt --------
__global__ void knorm_x(const float* __restrict__ s, float* __restrict__ invn) {
  int i = blockIdx.x, n = blockIdx.y;
  int tid = threadIdx.x;  // 128
  __shared__ float colsum[128];
  const float* sp = s + ((size_t)(n * 128 + i)) * 128;
  float a = 0.f;
#pragma unroll
  for (int dy = 0; dy < 16; ++dy) a += sp[dy * 128 + tid];
  colsum[tid] = a;
  __syncthreads();
  if (tid < 113) {
    float acc = 0.f;
#pragma unroll
    for (int dx = 0; dx < 16; ++dx) acc += colsum[tid + dx];
    invn[((size_t)n * 113 + i) * 113 + tid] = 1.0f / sqrtf(acc);
  }
}

// ---------------- Kernel E: main implicit-GEMM conv -----------------------
// R9: ABANDON 32x32 (R7/R8: unexplained residual conflicts, 471us). Back to
// 16x16x32 + 3-bit XOR (measured 0 conflicts). LDS pipe at 395us ran ~90%
// of ~112B/cyc/CU while MFMA 63% -> cut LDS bytes/output 2x: block =
// ROW-PAIR (i0=2p, i0+1) x n. 4 waves of M64(j) x N64(o): wave (iw,jh) owns
// output row i0+iw, j-half jh, ALL 64 o. Per wave-t: 8 A ds_reads (as
// before) but 32 MFMA / 2x output -> A-LDS per output halved; B loads 8/t
// (2x) with 2x MFMA cover, L2-resident. Staging: rows i0+dy, i0+1+dy share
// 15/16 -> 3x16KB rotating window, ONE row staged per dy (staging bytes /
// output also halved). 48KB LDS -> 3 blocks/CU = 12 waves (= baseline).
// Grid 57x16 = 912 = 8*114 -> same proven XCD chunking (2 images/XCD).
// Row 113 (p=56, iw=1) computed and discarded; staging h clamped to 127.
__launch_bounds__(256, 3)
__global__ void kconv(const unsigned short* __restrict__ x_t,
                      const unsigned short* __restrict__ y_t2,
                      const float* __restrict__ invn,
                      float* __restrict__ out) {
  int lin = blockIdx.y * 57 + blockIdx.x;
  int wg = (lin & 7) * 114 + (lin >> 3);   // bijective: 912 = 8*114
  int p = wg % 57;
  int n = wg / 57;
  int i0 = p * 2;
  int tid = threadIdx.x;
  int lane = tid & 63, wave = tid >> 6;
  int lane15 = lane & 15, q = lane >> 4;
  int iw = wave >> 1;       // output row within the pair
  int jh = wave & 1;        // j half (0: 0-63, 1: 64-127)

  __shared__ __align__(16) char smem[49152];  // 3 rotating 16KB row buffers

  const char* xbase = (const char*)x_t + ((size_t)n * 128) * 16384;

  // Stage one h-row (16KB) into buffer k; linear DMA, 4 waves partition.
  auto stageRow = [&](int h, int k) {
    const char* src = xbase + (size_t)h * 16384;
    char* buf = smem + k * 16384;
#pragma unroll
    for (int it = 0; it < 4; ++it) {
      int chunk = it * 256 + wave * 64;  // wave-uniform LDS base
      async_g2l16(src + (chunk + lane) * 16, buf + chunk * 16);
    }
  };

  // B fragments for ALL 64 o: nt = 0..3 o-groups, cb = 0..1 c-halves.
  const short8* ybase = (const short8*)y_t2 + lane;
  auto loadB = [&](int t, short8 bf[4][2]) {
    const short8* pt = ybase + (size_t)t * 512;  // 512 short8 per t
#pragma unroll
    for (int nt = 0; nt < 4; ++nt) {
      bf[nt][0] = pt[nt * 128];
      bf[nt][1] = pt[nt * 128 + 64];
    }
  };

  float4v acc[4][4];
#pragma unroll
  for (int mt = 0; mt < 4; ++mt)
#pragma unroll
    for (int nt = 0; nt < 4; ++nt) acc[mt][nt] = (float4v){0.f, 0.f, 0.f, 0.f};

  int abase[4];
#pragma unroll
  for (int mt = 0; mt < 4; ++mt)
    abase[mt] = (jh * 64 + mt * 16 + lane15) * 128;  // w-row * 128B

  short8 b0[4][2], b1[4][2];
  stageRow(i0, 0);
  stageRow(i0 + 1, 1);   // i0+1 <= 113 <= 127: always valid
  loadB(0, b0);
  vmem_drain();
  __syncthreads();

  int r0 = 0;  // dy % 3
#pragma unroll 1
  for (int dy = 0; dy < 16; ++dy) {
    if (dy < 15) {
      int h = i0 + dy + 2;
      if (h > 127) h = 127;  // only p=56 late-dy; feeds discarded row 113
      __builtin_amdgcn_sched_barrier(0);
      stageRow(h, r0 + 2 >= 3 ? r0 - 1 : r0 + 2);
      __builtin_amdgcn_sched_barrier(0);
    }
    int rb = r0 + iw >= 3 ? r0 + iw - 3 : r0 + iw;
    const char* Ab = smem + rb * 16384;
#pragma unroll
    for (int dx = 0; dx < 16; ++dx) {
      int t = dy * 16 + dx;
      // compile-time ping-pong after unroll: no register copies
      short8(&bc)[4][2] = (dx & 1) ? b1 : b0;
      short8(&bn)[4][2] = (dx & 1) ? b0 : b1;
      if (t < 255) loadB(t + 1, bn);
      int xr = (lane15 + dx) & 7;
#pragma unroll
      for (int cb = 0; cb < 2; ++cb) {
        int aoff = dx * 128 + (((q + cb * 4) ^ xr) << 4);
#pragma unroll
        for (int mt = 0; mt < 4; ++mt) {
          short8 a = *(const short8*)(Ab + abase[mt] + aoff);
#pragma unroll
          for (int nt = 0; nt < 4; ++nt)
            acc[mt][nt] = __builtin_amdgcn_mfma_f32_16x16x32_bf16(a, bc[nt][cb], acc[mt][nt], 0, 0, 0);
        }
      }
    }
    // Drain: the 8 newest VMEM ops are dx=15's loadB (next t's B, stays in
    // flight); stageRow's 4 LDS-DMA are older -> landed. Next dy's earliest
    // consumer of this stage is dy+1 (A for row i0+1+(dy+1)) — safe.
    asm volatile("s_waitcnt vmcnt(8)" ::: "memory");
    __syncthreads();
    r0 = r0 == 2 ? 0 : r0 + 1;
  }

  // Epilogue: direct stores (R6-verified map). o = nt*16 + lane15,
  // j = jh*64 + mt*16 + q*4 + reg. Row i = i0 + iw; discard i > 112.
  int i = i0 + iw;
  if (i <= 112) {
    const float* ivp = invn + ((size_t)n * 113 + i) * 113;
    float* op = out + (size_t)n * 64 * 12769 + (size_t)i * 113;
    int jbase = jh * 64 + q * 4;
#pragma unroll
    for (int mt = 0; mt < 4; ++mt) {
      int j0 = jbase + mt * 16;
      if (j0 <= 108) {
        float4v iv = *(const float4v*)(ivp + j0);
#pragma unroll
        for (int nt = 0; nt < 4; ++nt) {
          int o = nt * 16 + lane15;
          float4v v = acc[mt][nt];
          float4v r;
          r[0] = fmaxf(v[0] * iv[0], 0.f);
          r[1] = fmaxf(v[1] * iv[1], 0.f);
          r[2] = fmaxf(v[2] * iv[2], 0.f);
          r[3] = fmaxf(v[3] * iv[3], 0.f);
          *(float4v*)(op + (size_t)o * 12769 + j0) = r;
        }
      } else if (j0 == 112) {
        float ivs = ivp[112];
#pragma unroll
        for (int nt = 0; nt < 4; ++nt) {
          int o = nt * 16 + lane15;
          op[(size_t)o * 12769 + 112] = fmaxf(acc[mt][nt][0] * ivs, 0.f);
        }
      }
    }
  }
}

extern "C" void kernel_launch(void* const* d_in, const int* in_sizes, int n_in,
                              void* d_out, int out_size, void* d_ws, size_t ws_size,
                              hipStream_t stream) {
  const float* x = (const float*)d_in[0];
  const float* y = (const float*)d_in[1];
  float* out = (float*)d_out;
  char* ws = (char*)d_ws;
  unsigned short* x_t = (unsigned short*)ws;                 // 33,554,432 B
  unsigned short* y_t2 = (unsigned short*)(ws + 33554432);   //  2,097,152 B
  float* s = (float*)(ws + 35651584);                        //  1,048,576 B
  float* invn = (float*)(ws + 36700160);                     //    817,216 B

  hipLaunchKernelGGL(knorm_y, dim3(64), dim3(256), 0, stream, y, y_t2);
  hipLaunchKernelGGL(ktrans_x, dim3(128, 16), dim3(256), 0, stream, x, x_t, s);
  hipLaunchKernelGGL(knorm_x, dim3(113, 16), dim3(128), 0, stream, s, invn);
  hipLaunchKernelGGL(kconv, dim3(57, 16), dim3(256), 0, stream, x_t, y_t2, invn, out);
}

// Round 11
// 546.042 us; speedup vs baseline: 1.1155x; 1.1155x over previous
//
#include <hip/hip_runtime.h>
#include <stdint.h>

#define GAS __attribute__((address_space(1)))
#define LAS __attribute__((address_space(3)))

typedef __attribute__((ext_vector_type(8))) short short8;
typedef __attribute__((ext_vector_type(4))) float float4v;
typedef __attribute__((ext_vector_type(4))) unsigned int uint4v;

__device__ __forceinline__ unsigned short f2bf(float f) {
  union { float f; unsigned int u; } v; v.f = f;
  unsigned int r = v.u + 0x7fffu + ((v.u >> 16) & 1u);
  return (unsigned short)(r >> 16);
}

__device__ __forceinline__ void async_g2l16(const void* g, void* l) {
  __builtin_amdgcn_global_load_lds((const GAS unsigned int*)g,
                                   (LAS unsigned int*)l, 16, 0, 0);
}

__device__ __forceinline__ void vmem_drain() {
  asm volatile("s_waitcnt vmcnt(0)" ::: "memory");
}

// ---- Kernel P: fused prep. Blocks 0..2047: ktrans_x; 2048..2111: knorm_y.
// (Independent work; fusing removes one launch + serialization gap and
// overlaps the tiny 64-block knorm_y with the BW-bound transpose.)
// knorm_y layout (16x16x32 B-operand map): fragment (og,cb) is 1KB;
// lane = q*16 + (o&15) holds o = og*16+(o&15), c = cb*32 + q*8 + j.
// ktrans_x: x (NCHW f32) -> x_t bf16 [n][h][w][c], 3-bit XOR chunk swizzle
// (chunk = cc ^ (w&7) — measured 0 bank conflicts with the 16-row A-read).
__global__ void kprep(const float* __restrict__ x, const float* __restrict__ y,
                      unsigned short* __restrict__ x_t, unsigned short* __restrict__ y_t2,
                      float* __restrict__ s) {
  int b = blockIdx.x;
  int tid = threadIdx.x;
  if (b >= 2048) {
    // ---------------- knorm_y ----------------
    int o = b - 2048;
    const float* yo = y + o * 16384;
    float sm = 0.f;
    for (int idx = tid; idx < 16384; idx += 256) { float v = yo[idx]; sm += v * v; }
    for (int off = 32; off; off >>= 1) sm += __shfl_down(sm, off, 64);
    __shared__ float red[4];
    if ((tid & 63) == 0) red[tid >> 6] = sm;
    __syncthreads();
    float rn = 1.0f / sqrtf(red[0] + red[1] + red[2] + red[3]);
    int og = o >> 4, ol = o & 15;
    for (int idx = tid; idx < 16384; idx += 256) {
      int c = idx >> 8, dy = (idx >> 4) & 15, dx = idx & 15;
      int t = dy * 16 + dx;
      int cb = c >> 5, q = (c >> 3) & 3, j = c & 7;
      size_t dst = (size_t)t * 4096 + (size_t)(og * 2 + cb) * 512 + (q * 16 + ol) * 8 + j;
      y_t2[dst] = f2bf(yo[idx] * rn);
    }
    return;
  }
  // ---------------- ktrans_x ----------------
  int h = b & 127, n = b >> 7;
  __shared__ __align__(16) unsigned short tb[8192];
  __shared__ float sb[256];
  const float* xb = x + ((size_t)n * 64) * 16384 + h * 128;
  int w = tid & 127, half = tid >> 7;
  float acc = 0.f;
#pragma unroll
  for (int cs = 0; cs < 4; ++cs) {
    short8 tmp;
#pragma unroll
    for (int j = 0; j < 8; ++j) {
      int c = half * 32 + cs * 8 + j;
      float v = xb[(size_t)c * 16384 + w];
      tmp[j] = (short)f2bf(v);
      acc += v * v;
    }
    int chunk = (half * 4 + cs) ^ (w & 7);
    *(short8*)(tb + w * 64 + chunk * 8) = tmp;
  }
  sb[tid] = acc;
  __syncthreads();
  uint4v* dst = (uint4v*)(x_t + ((size_t)(n * 128 + h)) * 8192);
  const uint4v* src = (const uint4v*)tb;
  for (int idx = tid; idx < 1024; idx += 256) dst[idx] = src[idx];
  if (tid < 128) s[((size_t)(n * 128 + h)) * 128 + tid] = sb[tid] + sb[tid + 128];
}

// ---------------- Kernel D: separable 16x16 box sum of s -> 1/sqrt --------
__global__ void knorm_x(const float* __restrict__ s, float* __restrict__ invn) {
  int i = blockIdx.x, n = blockIdx.y;
  int tid = threadIdx.x;  // 128
  __shared__ float colsum[128];
  const float* sp = s + ((size_t)(n * 128 + i)) * 128;
  float a = 0.f;
#pragma unroll
  for (int dy = 0; dy < 16; ++dy) a += sp[dy * 128 + tid];
  colsum[tid] = a;
  __syncthreads();
  if (tid < 113) {
    float acc = 0.f;
#pragma unroll
    for (int dx = 0; dx < 16; ++dx) acc += colsum[tid + dx];
    invn[((size_t)n * 113 + i) * 113 + tid] = 1.0f / sqrtf(acc);
  }
}

// ---------------- Kernel E: main implicit-GEMM conv -----------------------
// R10: REVERT to the verified 395us R4 structure (5 structural rewrites all
// regressed: R3 64x64 473us, R5 depth3+prio 407, R6 n-pair 491, R7/R8 32x32
// 476/471, R9 row-pair 502 — the 1808-block/4-wave/small-state region is the
// optimum; LDS BW was never binding, 73% of ceiling at best). SINGLE probe
// vs that base: isolated s_setprio(1/0) around the MFMA cluster (T5; R5's
// test was confounded by depth-3's VGPR/occupancy cost). 3 desynced
// blocks/CU = the wave-role-diversity regime where T5 pays.
__launch_bounds__(256, 4)
__global__ void kconv(const unsigned short* __restrict__ x_t,
                      const unsigned short* __restrict__ y_t2,
                      const float* __restrict__ invn,
                      float* __restrict__ out) {
  // XCD-chunked swizzle: hw round-robins linear wg id across 8 XCDs.
  int lin = blockIdx.y * 113 + blockIdx.x;
  int wg = (lin & 7) * 226 + (lin >> 3);   // bijective: 1808 = 8*226
  int i = wg % 113;
  int n = wg / 113;
  int tid = threadIdx.x;
  int lane = tid & 63, wave = tid >> 6;
  int lane15 = lane & 15, q = lane >> 4;
  int wrow = wave >> 1, wcol = wave & 1;

  __shared__ __align__(16) char smem[32768];
  char* const A0 = smem;
  char* const A1 = smem + 16384;

  const char* xrow0 = (const char*)(x_t + ((size_t)(n * 128 + i)) * 8192);

  auto stageA = [&](int dy, char* buf) {
    const char* src = xrow0 + (size_t)dy * 16384;
#pragma unroll
    for (int it = 0; it < 4; ++it) {
      int chunk = it * 256 + wave * 64;  // wave-uniform LDS base
      async_g2l16(src + (chunk + lane) * 16, buf + chunk * 16);
    }
  };

  const short8* ybase = (const short8*)(y_t2 + (size_t)wcol * 2048 + (size_t)lane * 8);
  auto loadB = [&](int t, short8 bf[2][2]) {
    const short8* p = ybase + (size_t)t * 512;  // 512 short8 = 4096 shorts per t
    bf[0][0] = p[0];
    bf[0][1] = p[64];
    bf[1][0] = p[128];
    bf[1][1] = p[192];
  };

  float4v acc[4][2];
#pragma unroll
  for (int mt = 0; mt < 4; ++mt)
#pragma unroll
    for (int nt = 0; nt < 2; ++nt) acc[mt][nt] = (float4v){0.f, 0.f, 0.f, 0.f};

  int abase[4];
#pragma unroll
  for (int mt = 0; mt < 4; ++mt) abase[mt] = (wrow * 64 + mt * 16 + lane15) * 128;

  short8 b0[2][2], b1[2][2];
  stageA(0, A0);
  loadB(0, b0);
  vmem_drain();
  __syncthreads();

#pragma unroll 1
  for (int dy = 0; dy < 16; ++dy) {
    char* Ab = (dy & 1) ? A1 : A0;
    if (dy < 15) {
      __builtin_amdgcn_sched_barrier(0);
      stageA(dy + 1, (dy & 1) ? A0 : A1);
      __builtin_amdgcn_sched_barrier(0);
    }
#pragma unroll
    for (int dx = 0; dx < 16; ++dx) {
      int t = dy * 16 + dx;
      // compile-time ping-pong after unroll: no register copies
      short8(&bc)[2][2] = (dx & 1) ? b1 : b0;
      short8(&bn)[2][2] = (dx & 1) ? b0 : b1;
      if (t < 255) loadB(t + 1, bn);
      int xr = (lane15 + dx) & 7;
      __builtin_amdgcn_s_setprio(1);
#pragma unroll
      for (int cb = 0; cb < 2; ++cb) {
        int aoff = dx * 128 + (((q + cb * 4) ^ xr) << 4);
#pragma unroll
        for (int mt = 0; mt < 4; ++mt) {
          short8 a = *(const short8*)(Ab + abase[mt] + aoff);
          acc[mt][0] = __builtin_amdgcn_mfma_f32_16x16x32_bf16(a, bc[0][cb], acc[mt][0], 0, 0, 0);
          acc[mt][1] = __builtin_amdgcn_mfma_f32_16x16x32_bf16(a, bc[1][cb], acc[mt][1], 0, 0, 0);
        }
      }
      __builtin_amdgcn_s_setprio(0);
    }
    // Relaxed drain: all stageA LDS-DMA (pinned oldest by sched_barrier) must
    // land; the 4 newest (dx=15 loadB for next dy) may stay in flight.
    asm volatile("s_waitcnt vmcnt(4)" ::: "memory");
    __syncthreads();
  }

  // Epilogue: two-pass transpose through LDS (o-halves), fuse invn + relu.
  float* cs = (float*)smem;        // 32 x 132 floats = 16896 B
  float* ivs = cs + 4352;          // 128 floats
  const float* ivp = invn + ((size_t)n * 113 + i) * 113;
  if (tid < 128) ivs[tid] = (tid < 113) ? ivp[tid] : 0.f;
  float* op = out + (size_t)n * 64 * 12769 + (size_t)i * 113;
#pragma unroll 1
  for (int p = 0; p < 2; ++p) {
    if (wcol == p) {
#pragma unroll
      for (int mt = 0; mt < 4; ++mt)
#pragma unroll
        for (int nt = 0; nt < 2; ++nt) {
          int row = nt * 16 + lane15;
          int j0 = wrow * 64 + mt * 16 + q * 4;
          *(float4v*)(cs + row * 132 + j0) = acc[mt][nt];
        }
    }
    __syncthreads();
    for (int idx = tid; idx < 4096; idx += 256) {
      int o2 = idx >> 7, j = idx & 127;
      if (j < 113) {
        float v = cs[o2 * 132 + j] * ivs[j];
        op[(size_t)(p * 32 + o2) * 12769 + j] = fmaxf(v, 0.f);
      }
    }
    __syncthreads();
  }
}

extern "C" void kernel_launch(void* const* d_in, const int* in_sizes, int n_in,
                              void* d_out, int out_size, void* d_ws, size_t ws_size,
                              hipStream_t stream) {
  const float* x = (const float*)d_in[0];
  const float* y = (const float*)d_in[1];
  float* out = (float*)d_out;
  char* ws = (char*)d_ws;
  unsigned short* x_t = (unsigned short*)ws;                 // 33,554,432 B
  unsigned short* y_t2 = (unsigned short*)(ws + 33554432);   //  2,097,152 B
  float* s = (float*)(ws + 35651584);                        //  1,048,576 B
  float* invn = (float*)(ws + 36700160);                     //    817,216 B

  hipLaunchKernelGGL(kprep, dim3(2112), dim3(256), 0, stream, x, y, x_t, y_t2, s);
  hipLaunchKernelGGL(knorm_x, dim3(113, 16), dim3(128), 0, stream, s, invn);
  hipLaunchKernelGGL(kconv, dim3(113, 16), dim3(256), 0, stream, x_t, y_t2, invn, out);
}

// Round 12
// 531.726 us; speedup vs baseline: 1.1455x; 1.0269x over previous
//
#include <hip/hip_runtime.h>
#include <stdint.h>

#define GAS __attribute__((address_space(1)))
#define LAS __attribute__((address_space(3)))

typedef __attribute__((ext_vector_type(8))) short short8;
typedef __attribute__((ext_vector_type(4))) float float4v;
typedef __attribute__((ext_vector_type(4))) unsigned int uint4v;

__device__ __forceinline__ unsigned short f2bf(float f) {
  union { float f; unsigned int u; } v; v.f = f;
  unsigned int r = v.u + 0x7fffu + ((v.u >> 16) & 1u);
  return (unsigned short)(r >> 16);
}

__device__ __forceinline__ void async_g2l16(const void* g, void* l) {
  __builtin_amdgcn_global_load_lds((const GAS unsigned int*)g,
                                   (LAS unsigned int*)l, 16, 0, 0);
}

__device__ __forceinline__ void vmem_drain() {
  asm volatile("s_waitcnt vmcnt(0)" ::: "memory");
}

// ---- Kernel P: fused prep. Blocks 0..2047: ktrans_x; 2048..2111: knorm_y.
// knorm_y layout (16x16x32 B-operand map): fragment (og,cb) is 1KB;
// lane = q*16 + (o&15) holds o = og*16+(o&15), c = cb*32 + q*8 + j.
// ktrans_x: x (NCHW f32) -> x_t bf16 [n][h][w][c], 3-bit XOR chunk swizzle
// (chunk = cc ^ (w&7) — measured 0 bank conflicts with the 16-row A-read).
__global__ void kprep(const float* __restrict__ x, const float* __restrict__ y,
                      unsigned short* __restrict__ x_t, unsigned short* __restrict__ y_t2,
                      float* __restrict__ s) {
  int b = blockIdx.x;
  int tid = threadIdx.x;
  if (b >= 2048) {
    // ---------------- knorm_y ----------------
    int o = b - 2048;
    const float* yo = y + o * 16384;
    float sm = 0.f;
    for (int idx = tid; idx < 16384; idx += 256) { float v = yo[idx]; sm += v * v; }
    for (int off = 32; off; off >>= 1) sm += __shfl_down(sm, off, 64);
    __shared__ float red[4];
    if ((tid & 63) == 0) red[tid >> 6] = sm;
    __syncthreads();
    float rn = 1.0f / sqrtf(red[0] + red[1] + red[2] + red[3]);
    int og = o >> 4, ol = o & 15;
    for (int idx = tid; idx < 16384; idx += 256) {
      int c = idx >> 8, dy = (idx >> 4) & 15, dx = idx & 15;
      int t = dy * 16 + dx;
      int cb = c >> 5, q = (c >> 3) & 3, j = c & 7;
      size_t dst = (size_t)t * 4096 + (size_t)(og * 2 + cb) * 512 + (q * 16 + ol) * 8 + j;
      y_t2[dst] = f2bf(yo[idx] * rn);
    }
    return;
  }
  // ---------------- ktrans_x ----------------
  int h = b & 127, n = b >> 7;
  __shared__ __align__(16) unsigned short tb[8192];
  __shared__ float sb[256];
  const float* xb = x + ((size_t)n * 64) * 16384 + h * 128;
  int w = tid & 127, half = tid >> 7;
  float acc = 0.f;
#pragma unroll
  for (int cs = 0; cs < 4; ++cs) {
    short8 tmp;
#pragma unroll
    for (int j = 0; j < 8; ++j) {
      int c = half * 32 + cs * 8 + j;
      float v = xb[(size_t)c * 16384 + w];
      tmp[j] = (short)f2bf(v);
      acc += v * v;
    }
    int chunk = (half * 4 + cs) ^ (w & 7);
    *(short8*)(tb + w * 64 + chunk * 8) = tmp;
  }
  sb[tid] = acc;
  __syncthreads();
  uint4v* dst = (uint4v*)(x_t + ((size_t)(n * 128 + h)) * 8192);
  const uint4v* src = (const uint4v*)tb;
  for (int idx = tid; idx < 1024; idx += 256) dst[idx] = src[idx];
  if (tid < 128) s[((size_t)(n * 128 + h)) * 128 + tid] = sb[tid] + sb[tid + 128];
}

// ---------------- Kernel E: main implicit-GEMM conv + fused invn ----------
// R11: base = verified 395us R4 structure (XCD swizzle, depth-1 ping-pong,
// vmcnt(4), sched_barrier-pinned stageA; setprio REMOVED — isolated A/B
// showed -11us). NEW: (1) knorm_x folded into the prologue (same grid, zero
// duplication; 2048 L2 loads hidden under the initial stageA/loadB DMA) —
// kills one kernel launch + one dependency gap; (2) direct-store epilogue
// (R3/R9-verified map o = wcol*32+nt*16+lane15, j = wrow*64+mt*16+q*4+reg;
// q-groups give 64B-contiguous segments) — removes the 2-pass LDS transpose
// and 4 barriers.
__launch_bounds__(256, 4)
__global__ void kconv(const unsigned short* __restrict__ x_t,
                      const unsigned short* __restrict__ y_t2,
                      const float* __restrict__ s,
                      float* __restrict__ out) {
  // XCD-chunked swizzle: hw round-robins linear wg id across 8 XCDs.
  int lin = blockIdx.y * 113 + blockIdx.x;
  int wg = (lin & 7) * 226 + (lin >> 3);   // bijective: 1808 = 8*226
  int i = wg % 113;
  int n = wg / 113;
  int tid = threadIdx.x;
  int lane = tid & 63, wave = tid >> 6;
  int lane15 = lane & 15, q = lane >> 4;
  int wrow = wave >> 1, wcol = wave & 1;

  __shared__ __align__(16) char smem[32768];
  __shared__ float csum[128];
  __shared__ __align__(16) float ivs[128];
  char* const A0 = smem;
  char* const A1 = smem + 16384;

  const char* xrow0 = (const char*)(x_t + ((size_t)(n * 128 + i)) * 8192);

  auto stageA = [&](int dy, char* buf) {
    const char* src = xrow0 + (size_t)dy * 16384;
#pragma unroll
    for (int it = 0; it < 4; ++it) {
      int chunk = it * 256 + wave * 64;  // wave-uniform LDS base
      async_g2l16(src + (chunk + lane) * 16, buf + chunk * 16);
    }
  };

  const short8* ybase = (const short8*)(y_t2 + (size_t)wcol * 2048 + (size_t)lane * 8);
  auto loadB = [&](int t, short8 bf[2][2]) {
    const short8* p = ybase + (size_t)t * 512;  // 512 short8 = 4096 shorts per t
    bf[0][0] = p[0];
    bf[0][1] = p[64];
    bf[1][0] = p[128];
    bf[1][1] = p[192];
  };

  float4v acc[4][2];
#pragma unroll
  for (int mt = 0; mt < 4; ++mt)
#pragma unroll
    for (int nt = 0; nt < 2; ++nt) acc[mt][nt] = (float4v){0.f, 0.f, 0.f, 0.f};

  int abase[4];
#pragma unroll
  for (int mt = 0; mt < 4; ++mt) abase[mt] = (wrow * 64 + mt * 16 + lane15) * 128;

  short8 b0[2][2], b1[2][2];
  stageA(0, A0);
  loadB(0, b0);

  // ---- fused knorm_x (separable 16x16 box sum of s -> 1/sqrt), hidden
  // under the initial stage/load latency ----
  {
    const float* sp = s + ((size_t)(n * 128 + i)) * 128;
    if (tid < 128) {
      float a = 0.f;
#pragma unroll
      for (int dy = 0; dy < 16; ++dy) a += sp[dy * 128 + tid];
      csum[tid] = a;
    }
    __syncthreads();
    if (tid < 113) {
      float a = 0.f;
#pragma unroll
      for (int dx = 0; dx < 16; ++dx) a += csum[tid + dx];
      ivs[tid] = 1.0f / sqrtf(a);
    }
  }

  vmem_drain();
  __syncthreads();

#pragma unroll 1
  for (int dy = 0; dy < 16; ++dy) {
    char* Ab = (dy & 1) ? A1 : A0;
    if (dy < 15) {
      __builtin_amdgcn_sched_barrier(0);
      stageA(dy + 1, (dy & 1) ? A0 : A1);
      __builtin_amdgcn_sched_barrier(0);
    }
#pragma unroll
    for (int dx = 0; dx < 16; ++dx) {
      int t = dy * 16 + dx;
      // compile-time ping-pong after unroll: no register copies
      short8(&bc)[2][2] = (dx & 1) ? b1 : b0;
      short8(&bn)[2][2] = (dx & 1) ? b0 : b1;
      if (t < 255) loadB(t + 1, bn);
      int xr = (lane15 + dx) & 7;
#pragma unroll
      for (int cb = 0; cb < 2; ++cb) {
        int aoff = dx * 128 + (((q + cb * 4) ^ xr) << 4);
#pragma unroll
        for (int mt = 0; mt < 4; ++mt) {
          short8 a = *(const short8*)(Ab + abase[mt] + aoff);
          acc[mt][0] = __builtin_amdgcn_mfma_f32_16x16x32_bf16(a, bc[0][cb], acc[mt][0], 0, 0, 0);
          acc[mt][1] = __builtin_amdgcn_mfma_f32_16x16x32_bf16(a, bc[1][cb], acc[mt][1], 0, 0, 0);
        }
      }
    }
    // Relaxed drain: all stageA LDS-DMA (pinned oldest by sched_barrier) must
    // land; the 4 newest (dx=15 loadB for next dy) may stay in flight.
    asm volatile("s_waitcnt vmcnt(4)" ::: "memory");
    __syncthreads();
  }

  // Epilogue: direct stores, invn (from LDS) + relu fused.
  // o = wcol*32 + nt*16 + lane15; j = wrow*64 + mt*16 + q*4 + reg.
  float* op = out + (size_t)n * 64 * 12769 + (size_t)i * 113;
  int obase = wcol * 32 + lane15;
  int jb = wrow * 64 + q * 4;
#pragma unroll
  for (int mt = 0; mt < 4; ++mt) {
    int j0 = jb + mt * 16;
    if (j0 <= 108) {
      float4v iv = *(const float4v*)(ivs + j0);
#pragma unroll
      for (int nt = 0; nt < 2; ++nt) {
        int o = obase + nt * 16;
        float4v v = acc[mt][nt];
        float4v r;
        r[0] = fmaxf(v[0] * iv[0], 0.f);
        r[1] = fmaxf(v[1] * iv[1], 0.f);
        r[2] = fmaxf(v[2] * iv[2], 0.f);
        r[3] = fmaxf(v[3] * iv[3], 0.f);
        *(float4v*)(op + (size_t)o * 12769 + j0) = r;
      }
    } else if (j0 == 112) {
      float ivv = ivs[112];
#pragma unroll
      for (int nt = 0; nt < 2; ++nt) {
        int o = obase + nt * 16;
        op[(size_t)o * 12769 + 112] = fmaxf(acc[mt][nt][0] * ivv, 0.f);
      }
    }
  }
}

extern "C" void kernel_launch(void* const* d_in, const int* in_sizes, int n_in,
                              void* d_out, int out_size, void* d_ws, size_t ws_size,
                              hipStream_t stream) {
  const float* x = (const float*)d_in[0];
  const float* y = (const float*)d_in[1];
  float* out = (float*)d_out;
  char* ws = (char*)d_ws;
  unsigned short* x_t = (unsigned short*)ws;                 // 33,554,432 B
  unsigned short* y_t2 = (unsigned short*)(ws + 33554432);   //  2,097,152 B
  float* s = (float*)(ws + 35651584);                        //  1,048,576 B

  hipLaunchKernelGGL(kprep, dim3(2112), dim3(256), 0, stream, x, y, x_t, y_t2, s);
  hipLaunchKernelGGL(kconv, dim3(113, 16), dim3(256), 0, stream, x_t, y_t2, s, out);
}

// Round 14
// 513.697 us; speedup vs baseline: 1.1857x; 1.0351x over previous
//
#include <hip/hip_runtime.h>
#include <stdint.h>

#define GAS __attribute__((address_space(1)))
#define LAS __attribute__((address_space(3)))

typedef __attribute__((ext_vector_type(8))) short short8;
typedef __attribute__((ext_vector_type(4))) float float4v;
typedef __attribute__((ext_vector_type(4))) unsigned int uint4v;

__device__ __forceinline__ unsigned short f2bf(float f) {
  union { float f; unsigned int u; } v; v.f = f;
  unsigned int r = v.u + 0x7fffu + ((v.u >> 16) & 1u);
  return (unsigned short)(r >> 16);
}

__device__ __forceinline__ void async_g2l16(const void* g, void* l) {
  __builtin_amdgcn_global_load_lds((const GAS unsigned int*)g,
                                   (LAS unsigned int*)l, 16, 0, 0);
}

__device__ __forceinline__ void vmem_drain() {
  asm volatile("s_waitcnt vmcnt(0)" ::: "memory");
}

// ---- Kernel P: fused prep. Blocks 0..255: knorm_y (4 segs/o, placed FIRST
// so the scattered fragment writes overlap the BW-bound transpose instead of
// tailing it). Blocks 256..2303: ktrans_x with float4-vectorized reads (was
// 32 scalar loads/thread — G13 violation; 4x fewer load instructions).
// knorm_y layout (16x16x32 B-operand map): fragment (og,cb) is 1KB;
// lane = q*16 + (o&15) holds o = og*16+(o&15), c = cb*32 + q*8 + j.
// ktrans_x: x (NCHW f32) -> x_t bf16 [n][h][w][c], 3-bit XOR chunk swizzle
// (chunk = (c/8) ^ (w&7) — measured 0 bank conflicts with the 16-row A-read).
__global__ void kprep(const float* __restrict__ x, const float* __restrict__ y,
                      unsigned short* __restrict__ x_t, unsigned short* __restrict__ y_t2,
                      float* __restrict__ s) {
  int b = blockIdx.x;
  int tid = threadIdx.x;
  if (b < 256) {
    // ---------------- knorm_y: block = (o, quarter-segment) ----------------
    int o = b >> 2, seg = b & 3;
    const float* yo = y + o * 16384;
    // Full-o norm (redundant per seg; 3x extra reads are L2-hot, ~2us total)
    const float4v* yo4 = (const float4v*)yo;
    float sm = 0.f;
    for (int p = tid; p < 4096; p += 256) {
      float4v t4 = yo4[p];
      sm += t4[0] * t4[0] + t4[1] * t4[1] + t4[2] * t4[2] + t4[3] * t4[3];
    }
    for (int off = 32; off; off >>= 1) sm += __shfl_down(sm, off, 64);
    __shared__ float red[4];
    if ((tid & 63) == 0) red[tid >> 6] = sm;
    __syncthreads();
    float rn = 1.0f / sqrtf(red[0] + red[1] + red[2] + red[3]);
    int og = o >> 4, ol = o & 15;
    int end = seg * 4096 + 4096;
    for (int idx = seg * 4096 + tid; idx < end; idx += 256) {
      int c = idx >> 8, dy = (idx >> 4) & 15, dx = idx & 15;
      int t = dy * 16 + dx;
      int cb = c >> 5, q = (c >> 3) & 3, j = c & 7;
      size_t dst = (size_t)t * 4096 + (size_t)(og * 2 + cb) * 512 + (q * 16 + ol) * 8 + j;
      y_t2[dst] = f2bf(yo[idx] * rn);
    }
    return;
  }
  // ---------------- ktrans_x: thread (wq, cg) = 4 w x 8 c ----------------
  int bb = b - 256;
  int h = bb & 127, n = bb >> 7;
  __shared__ __align__(16) unsigned short tb[8192];
  __shared__ float sb[1024];  // [cg][w] partial sums
  const float* xb = x + ((size_t)n * 64) * 16384 + h * 128;
  int wq = tid & 31, cg = tid >> 5;
  float4v v[8];
#pragma unroll
  for (int j = 0; j < 8; ++j)
    v[j] = *(const float4v*)(xb + (size_t)(cg * 8 + j) * 16384 + wq * 4);
  float4v a = (float4v){0.f, 0.f, 0.f, 0.f};
#pragma unroll
  for (int j = 0; j < 8; ++j) {
    a[0] += v[j][0] * v[j][0];
    a[1] += v[j][1] * v[j][1];
    a[2] += v[j][2] * v[j][2];
    a[3] += v[j][3] * v[j][3];
  }
#pragma unroll
  for (int k = 0; k < 4; ++k) sb[cg * 128 + wq * 4 + k] = a[k];
#pragma unroll
  for (int k = 0; k < 4; ++k) {
    int w = wq * 4 + k;
    short8 tmp;
#pragma unroll
    for (int j = 0; j < 8; ++j) tmp[j] = (short)f2bf(v[j][k]);
    int chunk = cg ^ (w & 7);
    *(short8*)(tb + w * 64 + chunk * 8) = tmp;
  }
  __syncthreads();
  uint4v* dst = (uint4v*)(x_t + ((size_t)(n * 128 + h)) * 8192);
  const uint4v* src = (const uint4v*)tb;
  for (int idx = tid; idx < 1024; idx += 256) dst[idx] = src[idx];
  if (tid < 128) {
    float ssum = 0.f;
#pragma unroll
    for (int g = 0; g < 8; ++g) ssum += sb[g * 128 + tid];
    s[((size_t)(n * 128 + h)) * 128 + tid] = ssum;
  }
}

// ---------------- Kernel E: main implicit-GEMM conv + fused invn ----------
// (R12 structure, unchanged: verified 395-398us floor. XCD swizzle, depth-1
// B ping-pong, vmcnt(4), sched_barrier-pinned stageA, knorm_x folded into
// the prologue, direct-store epilogue with R3/R9-verified C/D map.)
__launch_bounds__(256, 4)
__global__ void kconv(const unsigned short* __restrict__ x_t,
                      const unsigned short* __restrict__ y_t2,
                      const float* __restrict__ s,
                      float* __restrict__ out) {
  // XCD-chunked swizzle: hw round-robins linear wg id across 8 XCDs.
  int lin = blockIdx.y * 113 + blockIdx.x;
  int wg = (lin & 7) * 226 + (lin >> 3);   // bijective: 1808 = 8*226
  int i = wg % 113;
  int n = wg / 113;
  int tid = threadIdx.x;
  int lane = tid & 63, wave = tid >> 6;
  int lane15 = lane & 15, q = lane >> 4;
  int wrow = wave >> 1, wcol = wave & 1;

  __shared__ __align__(16) char smem[32768];
  __shared__ float csum[128];
  __shared__ __align__(16) float ivs[128];
  char* const A0 = smem;
  char* const A1 = smem + 16384;

  const char* xrow0 = (const char*)(x_t + ((size_t)(n * 128 + i)) * 8192);

  auto stageA = [&](int dy, char* buf) {
    const char* src = xrow0 + (size_t)dy * 16384;
#pragma unroll
    for (int it = 0; it < 4; ++it) {
      int chunk = it * 256 + wave * 64;  // wave-uniform LDS base
      async_g2l16(src + (chunk + lane) * 16, buf + chunk * 16);
    }
  };

  const short8* ybase = (const short8*)(y_t2 + (size_t)wcol * 2048 + (size_t)lane * 8);
  auto loadB = [&](int t, short8 bf[2][2]) {
    const short8* p = ybase + (size_t)t * 512;  // 512 short8 = 4096 shorts per t
    bf[0][0] = p[0];
    bf[0][1] = p[64];
    bf[1][0] = p[128];
    bf[1][1] = p[192];
  };

  float4v acc[4][2];
#pragma unroll
  for (int mt = 0; mt < 4; ++mt)
#pragma unroll
    for (int nt = 0; nt < 2; ++nt) acc[mt][nt] = (float4v){0.f, 0.f, 0.f, 0.f};

  int abase[4];
#pragma unroll
  for (int mt = 0; mt < 4; ++mt) abase[mt] = (wrow * 64 + mt * 16 + lane15) * 128;

  short8 b0[2][2], b1[2][2];
  stageA(0, A0);
  loadB(0, b0);

  // ---- fused knorm_x (separable 16x16 box sum of s -> 1/sqrt), hidden
  // under the initial stage/load latency ----
  {
    const float* sp = s + ((size_t)(n * 128 + i)) * 128;
    if (tid < 128) {
      float a = 0.f;
#pragma unroll
      for (int dy = 0; dy < 16; ++dy) a += sp[dy * 128 + tid];
      csum[tid] = a;
    }
    __syncthreads();
    if (tid < 113) {
      float a = 0.f;
#pragma unroll
      for (int dx = 0; dx < 16; ++dx) a += csum[tid + dx];
      ivs[tid] = 1.0f / sqrtf(a);
    }
  }

  vmem_drain();
  __syncthreads();

#pragma unroll 1
  for (int dy = 0; dy < 16; ++dy) {
    char* Ab = (dy & 1) ? A1 : A0;
    if (dy < 15) {
      __builtin_amdgcn_sched_barrier(0);
      stageA(dy + 1, (dy & 1) ? A0 : A1);
      __builtin_amdgcn_sched_barrier(0);
    }
#pragma unroll
    for (int dx = 0; dx < 16; ++dx) {
      int t = dy * 16 + dx;
      // compile-time ping-pong after unroll: no register copies
      short8(&bc)[2][2] = (dx & 1) ? b1 : b0;
      short8(&bn)[2][2] = (dx & 1) ? b0 : b1;
      if (t < 255) loadB(t + 1, bn);
      int xr = (lane15 + dx) & 7;
#pragma unroll
      for (int cb = 0; cb < 2; ++cb) {
        int aoff = dx * 128 + (((q + cb * 4) ^ xr) << 4);
#pragma unroll
        for (int mt = 0; mt < 4; ++mt) {
          short8 a = *(const short8*)(Ab + abase[mt] + aoff);
          acc[mt][0] = __builtin_amdgcn_mfma_f32_16x16x32_bf16(a, bc[0][cb], acc[mt][0], 0, 0, 0);
          acc[mt][1] = __builtin_amdgcn_mfma_f32_16x16x32_bf16(a, bc[1][cb], acc[mt][1], 0, 0, 0);
        }
      }
    }
    // Relaxed drain: all stageA LDS-DMA (pinned oldest by sched_barrier) must
    // land; the 4 newest (dx=15 loadB for next dy) may stay in flight.
    asm volatile("s_waitcnt vmcnt(4)" ::: "memory");
    __syncthreads();
  }

  // Epilogue: direct stores, invn (from LDS) + relu fused.
  // o = wcol*32 + nt*16 + lane15; j = wrow*64 + mt*16 + q*4 + reg.
  float* op = out + (size_t)n * 64 * 12769 + (size_t)i * 113;
  int obase = wcol * 32 + lane15;
  int jb = wrow * 64 + q * 4;
#pragma unroll
  for (int mt = 0; mt < 4; ++mt) {
    int j0 = jb + mt * 16;
    if (j0 <= 108) {
      float4v iv = *(const float4v*)(ivs + j0);
#pragma unroll
      for (int nt = 0; nt < 2; ++nt) {
        int o = obase + nt * 16;
        float4v v = acc[mt][nt];
        float4v r;
        r[0] = fmaxf(v[0] * iv[0], 0.f);
        r[1] = fmaxf(v[1] * iv[1], 0.f);
        r[2] = fmaxf(v[2] * iv[2], 0.f);
        r[3] = fmaxf(v[3] * iv[3], 0.f);
        *(float4v*)(op + (size_t)o * 12769 + j0) = r;
      }
    } else if (j0 == 112) {
      float ivv = ivs[112];
#pragma unroll
      for (int nt = 0; nt < 2; ++nt) {
        int o = obase + nt * 16;
        op[(size_t)o * 12769 + 112] = fmaxf(acc[mt][nt][0] * ivv, 0.f);
      }
    }
  }
}

extern "C" void kernel_launch(void* const* d_in, const int* in_sizes, int n_in,
                              void* d_out, int out_size, void* d_ws, size_t ws_size,
                              hipStream_t stream) {
  const float* x = (const float*)d_in[0];
  const float* y = (const float*)d_in[1];
  float* out = (float*)d_out;
  char* ws = (char*)d_ws;
  unsigned short* x_t = (unsigned short*)ws;                 // 33,554,432 B
  unsigned short* y_t2 = (unsigned short*)(ws + 33554432);   //  2,097,152 B
  float* s = (float*)(ws + 35651584);                        //  1,048,576 B

  hipLaunchKernelGGL(kprep, dim3(2304), dim3(256), 0, stream, x, y, x_t, y_t2, s);
  hipLaunchKernelGGL(kconv, dim3(113, 16), dim3(256), 0, stream, x_t, y_t2, s, out);
}